// Round 18
// baseline (88.747 us; speedup 1.0000x reference)
//
#include <hip/hip_runtime.h>
#include <hip/hip_bf16.h>
#include <math.h>

#define B 4
#define L 2048
#define D 256
#define H 8
#define HD 32
#define KVB 64
#define SCALE 0.17677669529663687f
#define LOG2E 1.4426950408889634f
#define QSCL (SCALE * LOG2E)

typedef __attribute__((ext_vector_type(8))) short short8;
typedef __attribute__((ext_vector_type(4))) short short4v;
typedef __attribute__((ext_vector_type(4))) float f32x4;

__device__ inline short f2bf(float x) {
  union { float f; unsigned u; } c; c.f = x;
  unsigned r = (c.u + 0x7FFFu + ((c.u >> 16) & 1u)) >> 16;
  return (short)r;
}
__device__ inline float bf2f(short s) {
  union { unsigned u; float f; } c;
  c.u = ((unsigned)(unsigned short)s) << 16;
  return c.f;
}

// async 16B global->LDS DMA: LDS dest is wave-uniform base + lane*16 (m104);
// global source is per-lane. Compiler cannot demote this prefetch (no regs).
#define GLOAD_LDS16(gp, lp)                                                  \
  __builtin_amdgcn_global_load_lds(                                          \
      (const __attribute__((address_space(1))) unsigned*)(const void*)(gp),  \
      (__attribute__((address_space(3))) unsigned*)(void*)(lp), 16, 0, 0)

// Session journal (counter-evidenced):
// R5/R6: permlane*_swap with duplicated inputs is NOT a reduce primitive ->
//   __shfl_xor for reductions.
// R10: register K/V prefetch gets demoted (VGPR 60) -> LDS staging via
//   global_load_lds (R11: 124->51us attn).
// R12/R13: tight launch_bounds caps -> under-allocation + scratch spill
//   (WRITE_SIZE 531/12 MB). (512,4) = clean 48 VGPR.
// R14: in-block KV-split clean but slower (64 vs 51us) -> reverted.
// R16: v_pk_add_f32 + v_dot2_f32_bf16 (unvalidated) -> absmax 2.19. Rule:
//   one unproven primitive per round, validated in isolation, or not at all.
// R17: qkv 32x64 tiles = +4us regression (2x B-traffic) -> revert to 64x64.
// R18: attn 4-buffer LDS rotation, one barrier per 2 tiles (barrier-only
//   semantics: every STAGE->read and read->overwrite crosses a sync).

// ---------------- prep_all: one launch for xb / bias / wqkvT / woutT --------
// grid sections: [0,1024) xb | [1024,3072) bias | [3072,3264) wqkvT |
// [3264,3328) woutT. 256 threads each.
__global__ __launch_bounds__(256) void prep_all(const float* __restrict__ x,
                                                const float* __restrict__ bias,
                                                const float* __restrict__ wqkv,
                                                const float* __restrict__ wout,
                                                short* __restrict__ xb,
                                                short* __restrict__ bp,
                                                short* __restrict__ wqkvT,
                                                short* __restrict__ woutT) {
  __shared__ short tile[32][33];
  int bid = blockIdx.x;
  if (bid < 1024) {
    // x f32 -> bf16
    int i = (bid * 256 + threadIdx.x) * 8;
    f32x4 a = *reinterpret_cast<const f32x4*>(x + i);
    f32x4 b = *reinterpret_cast<const f32x4*>(x + i + 4);
    short8 o;
#pragma unroll
    for (int j = 0; j < 4; ++j) { o[j] = f2bf(a[j]); o[4 + j] = f2bf(b[j]); }
    *reinterpret_cast<short8*>(xb + i) = o;
  } else if (bid < 3072) {
    // bias f32 [L][L] -> bf16 fragment-ordered, PRE-SCALED by LOG2E:
    // bp[q][kvt][g][i], i=4c+r  <->  bias[q][kvt*64 + 16c + g*4 + r] * LOG2E
    int base = ((bid - 1024) * 256 + threadIdx.x) * 8;
    int q = base >> 11;
    int rem = base & 2047;
    int kvt = rem >> 6;
    int wi = rem & 63;
    int g = wi >> 4;
    int c0 = (wi & 15) >> 2;       // 0 or 2
    const float* src = bias + (long)q * L + kvt * 64 + c0 * 16 + g * 4;
    f32x4 b0 = *reinterpret_cast<const f32x4*>(src);
    f32x4 b1 = *reinterpret_cast<const f32x4*>(src + 16);
    short8 o;
#pragma unroll
    for (int j = 0; j < 4; ++j) {
      o[j] = f2bf(b0[j] * LOG2E);
      o[4 + j] = f2bf(b1[j] * LOG2E);
    }
    *reinterpret_cast<short8*>(bp + base) = o;
  } else {
    // W [256,N] f32 -> W^T [N,256] bf16, LDS-tiled 32x32
    const float* w;
    short* wt;
    int idx, N;
    if (bid < 3264) { idx = bid - 3072; w = wqkv; wt = wqkvT; N = 768; }
    else            { idx = bid - 3264; w = wout; wt = woutT; N = 256; }
    int k0 = (idx & 7) * 32;
    int n0 = (idx >> 3) * 32;
    int tx = threadIdx.x & 31, ty = threadIdx.x >> 5;
#pragma unroll
    for (int i = 0; i < 32; i += 8)
      tile[ty + i][tx] = f2bf(w[(k0 + ty + i) * N + n0 + tx]);
    __syncthreads();
#pragma unroll
    for (int i = 0; i < 32; i += 8)
      wt[(n0 + ty + i) * 256 + k0 + tx] = tile[tx][ty + i];
  }
}

// ---------------- Kernel 1: qkv = xb @ Wqkv (64x64 tiles, R15-proven) -------
__global__ __launch_bounds__(64) void qkv_gemm(const short* __restrict__ xb,
                                               const short* __restrict__ wt,
                                               short* __restrict__ qb,
                                               short* __restrict__ kb,
                                               short* __restrict__ vt) {
  int bid = blockIdx.x;
  int mt = bid / 12, nt = bid % 12;
  int m0 = mt * 64, n0 = nt * 64;
  int l = threadIdx.x, ra = l & 15, g = l >> 4;

  f32x4 acc[4][4] = {};
  for (int k0 = 0; k0 < 256; k0 += 32) {
    int kk = k0 + g * 8;
    short8 bfr[4], afr[4];
#pragma unroll
    for (int nf = 0; nf < 4; ++nf)
      bfr[nf] = *reinterpret_cast<const short8*>(&wt[(n0 + nf * 16 + ra) * 256 + kk]);
#pragma unroll
    for (int mf = 0; mf < 4; ++mf)
      afr[mf] = *reinterpret_cast<const short8*>(&xb[(m0 + mf * 16 + ra) * 256 + kk]);
#pragma unroll
    for (int mf = 0; mf < 4; ++mf)
#pragma unroll
      for (int nf = 0; nf < 4; ++nf)
        acc[mf][nf] = __builtin_amdgcn_mfma_f32_16x16x32_bf16(afr[mf], bfr[nf], acc[mf][nf], 0, 0, 0);
  }

  int sec = n0 >> 8;   // 0=q 1=k 2=v (uniform per block)
  float scl = (sec == 0) ? QSCL : 1.0f;
#pragma unroll
  for (int nf = 0; nf < 4; ++nf) {
    int n = n0 + nf * 16 + ra;
    int c = n & 255;
    int h = c >> 5, d = c & 31;
#pragma unroll
    for (int mf = 0; mf < 4; ++mf) {
#pragma unroll
      for (int r = 0; r < 4; ++r) {
        int mm = m0 + mf * 16 + g * 4 + r;
        int b = mm >> 11, lpos = mm & 2047;
        short val = f2bf(acc[mf][nf][r] * scl);
        if (sec == 2) vt[((b * H + h) * HD + d) * L + lpos] = val;
        else {
          short* dst = (sec == 0) ? qb : kb;
          dst[((b * H + h) * L + lpos) * HD + d] = val;
        }
      }
    }
  }
}

// ---------------- Kernel 2: flash attention (4-buffer LDS, bar per 2 tiles) -
// Block = 8 waves (512 thr) = 1 head x 8 q-tiles (128 q-rows). Per 64-kv tile
// K (4KB) + V^T (4KB) staged in LDS fragment-ordered lane-contiguous
// [subtile][lane][16B]; wave w stages subtile w via 1 global_load_lds(16B).
// FOUR rotating buffers: stages for tiles t+2,t+3 issue at iteration top,
// TWO TILE computations (~1300cy) run before the barrier drains them.
// Safety (barrier-only): stage(buf,t) -> BAR -> read(buf,t); read(buf,t) ->
// BAR -> stage(buf,t+4). One __syncthreads per 2 tiles (17 total vs 33).
// Grid 512 = 2 blocks/CU, 64KB LDS/CU. XCD = bid&7 -> heads 4x..4x+3:
// K/V 1MB/XCD stays L2-resident (FETCH 39MB measured).
__global__ __launch_bounds__(512, 4) void attn_fwd(const short* __restrict__ qb,
                                                   const short* __restrict__ kb,
                                                   const short* __restrict__ vt,
                                                   const short* __restrict__ bp,
                                                   short* __restrict__ ob) {
  __shared__ short kvlds[4][8][512];   // [buf][subtile][lane*8] = 32 KB

  int wid = threadIdx.x >> 6;
  int l = threadIdx.x & 63;
  int ra = l & 15, g = l >> 4;
  bool oddg = (g & 1);
  int x = blockIdx.x & 7;              // XCD id under round-robin dispatch
  int y = (blockIdx.x >> 3) & 3;
  int qblk = blockIdx.x >> 5;          // 0..15
  int bh = x * 4 + y;
  int q0 = qblk * 128 + wid * 16;

  const short* kbase = kb + bh * (L * HD);
  const short* vbase = vt + bh * (HD * L);
  const short* bpbase = bp + (q0 + ra) * L + g * 16;

  short8 bq = *reinterpret_cast<const short8*>(qb + (bh * L + q0 + ra) * HD + g * 8);

  // Per-wave staging source (lane-resolved). Wave w<4 stages K subtile w
  // (rows 16w+ra, cols g*8..); wave w>=4 stages V subtile j=w-4
  // (rows (j>>1)*16+ra of V^T, cols kv+(j&1)*32+g*8).
  const short* gsrc0;
  int gstep;
  if (wid < 4) { gsrc0 = kbase + (16 * wid + ra) * HD + g * 8; gstep = KVB * HD; }
  else {
    int j = wid - 4;
    gsrc0 = vbase + ((j >> 1) * 16 + ra) * L + (j & 1) * 32 + g * 8;
    gstep = KVB;
  }

  f32x4 o0 = {}, o1 = {}, zf = {};
  float mrun = -1e30f, lsum = 0.f;
  short8 bbX[2], bbY[2];

  auto STAGE = [&](int buf, int t) {
    GLOAD_LDS16(gsrc0 + (size_t)t * gstep, &kvlds[buf][wid][0]);
  };
  auto BLOAD = [&](short8 (&bb)[2], int t) {
    const short* p = bpbase + t * KVB;
    bb[0] = *reinterpret_cast<const short8*>(p);
    bb[1] = *reinterpret_cast<const short8*>(p + 8);
  };

  auto TILE = [&](int buf, short8 (&bb)[2]) {
    const short* base = &kvlds[buf][0][0];
    short8 ak0 = *reinterpret_cast<const short8*>(base + 0 * 512 + l * 8);
    short8 ak1 = *reinterpret_cast<const short8*>(base + 1 * 512 + l * 8);
    short8 ak2 = *reinterpret_cast<const short8*>(base + 2 * 512 + l * 8);
    short8 ak3 = *reinterpret_cast<const short8*>(base + 3 * 512 + l * 8);
    short8 va0 = *reinterpret_cast<const short8*>(base + 4 * 512 + l * 8);
    short8 va1 = *reinterpret_cast<const short8*>(base + 5 * 512 + l * 8);
    short8 va2 = *reinterpret_cast<const short8*>(base + 6 * 512 + l * 8);
    short8 va3 = *reinterpret_cast<const short8*>(base + 7 * 512 + l * 8);

    f32x4 s0 = __builtin_amdgcn_mfma_f32_16x16x32_bf16(ak0, bq, zf, 0, 0, 0);
    f32x4 s1 = __builtin_amdgcn_mfma_f32_16x16x32_bf16(ak1, bq, zf, 0, 0, 0);
    f32x4 s2 = __builtin_amdgcn_mfma_f32_16x16x32_bf16(ak2, bq, zf, 0, 0, 0);
    f32x4 s3 = __builtin_amdgcn_mfma_f32_16x16x32_bf16(ak3, bq, zf, 0, 0, 0);

    // v = s + bias (bias pre-scaled by LOG2E in prep -> plain add, not fma)
    float v[16];
#pragma unroll
    for (int r = 0; r < 4; ++r) {
      v[r]      = s0[r] + bf2f(bb[0][r]);
      v[4 + r]  = s1[r] + bf2f(bb[0][4 + r]);
      v[8 + r]  = s2[r] + bf2f(bb[1][r]);
      v[12 + r] = s3[r] + bf2f(bb[1][4 + r]);
    }
    float t0 = fmaxf(fmaxf(v[0], v[1]), v[2]);
    float t1 = fmaxf(fmaxf(v[3], v[4]), v[5]);
    float t2 = fmaxf(fmaxf(v[6], v[7]), v[8]);
    float t3 = fmaxf(fmaxf(v[9], v[10]), v[11]);
    float t4m = fmaxf(fmaxf(v[12], v[13]), v[14]);
    float pml = fmaxf(fmaxf(fmaxf(t0, t1), t2), fmaxf(fmaxf(t3, t4m), v[15]));

    // mrun wave-uniform -> per-lane __all check; shfls only on rare rescale.
    if (!__all(pml <= mrun + 8.0f)) {
      float pm = fmaxf(pml, __shfl_xor(pml, 16));
      pm = fmaxf(pm, __shfl_xor(pm, 32));
      float mnew = fmaxf(mrun, pm);
      float ad = mrun - mnew, al;
      asm("v_exp_f32 %0, %1" : "=v"(al) : "v"(ad));
      lsum *= al;
#pragma unroll
      for (int r = 0; r < 4; ++r) { o0[r] *= al; o1[r] *= al; }
      mrun = mnew;
    }
    float m = mrun;
#pragma unroll
    for (int i = 0; i < 16; ++i) {
      float xv = v[i] - m;
      asm("v_exp_f32 %0, %1" : "=v"(v[i]) : "v"(xv));
    }
    // tree-reduce the per-lane partial (depth 4, not a 16-long serial chain)
    float p01 = (v[0] + v[1]) + (v[2] + v[3]);
    float p23 = (v[4] + v[5]) + (v[6] + v[7]);
    float p45 = (v[8] + v[9]) + (v[10] + v[11]);
    float p67 = (v[12] + v[13]) + (v[14] + v[15]);
    lsum += (p01 + p23) + (p45 + p67);

#pragma unroll
    for (int ch = 0; ch < 2; ++ch) {
      const float* pc = v + ch * 8;
      unsigned w01, w23, w45, w67;
      asm("v_cvt_pk_bf16_f32 %0, %1, %2" : "=v"(w01) : "v"(pc[0]), "v"(pc[1]));
      asm("v_cvt_pk_bf16_f32 %0, %1, %2" : "=v"(w23) : "v"(pc[2]), "v"(pc[3]));
      asm("v_cvt_pk_bf16_f32 %0, %1, %2" : "=v"(w45) : "v"(pc[4]), "v"(pc[5]));
      asm("v_cvt_pk_bf16_f32 %0, %1, %2" : "=v"(w67) : "v"(pc[6]), "v"(pc[7]));
      asm("v_permlane32_swap_b32 %0, %1" : "+v"(w01), "+v"(w45));  // distinct ops: proven
      asm("v_permlane32_swap_b32 %0, %1" : "+v"(w23), "+v"(w67));
      unsigned z1 = oddg ? w01 : w45;
      unsigned z2 = oddg ? w23 : w67;
      unsigned y1 = (unsigned)__shfl_xor((int)z1, 16);   // exact permute
      unsigned y2 = (unsigned)__shfl_xor((int)z2, 16);
      union { unsigned u[4]; short8 s; } pb;
      pb.u[0] = oddg ? y1 : w01;
      pb.u[1] = oddg ? y2 : w23;
      pb.u[2] = oddg ? w45 : y1;
      pb.u[3] = oddg ? w67 : y2;
      o0 = __builtin_amdgcn_mfma_f32_16x16x32_bf16(ch ? va1 : va0, pb.s, o0, 0, 0, 0);
      o1 = __builtin_amdgcn_mfma_f32_16x16x32_bf16(ch ? va3 : va2, pb.s, o1, 0, 0, 0);
    }
  };

  // ---- 4-buffer pipeline: stage t+2,t+3 at top; one barrier per 2 tiles ----
  STAGE(0, 0);
  STAGE(1, 1);
  BLOAD(bbX, 0);
  __syncthreads();                     // drains stages 0,1
  for (int t = 0; t < 32; t += 2) {
    int lo = t & 2;                    // 0,2,0,2,... buffer pair computing
    int slo = lo ^ 2;                  // pair being staged
    if (t + 2 < 32) { STAGE(slo, t + 2); STAGE(slo + 1, t + 3); }
    BLOAD(bbY, t + 1);
    TILE(lo, bbX);
    if (t + 2 < 32) BLOAD(bbX, t + 2);
    TILE(lo + 1, bbY);
    __syncthreads();                   // drains stages t+2,t+3; frees lo pair
  }

  int b = bh >> 3, h = bh & 7;
  float ls = lsum;
  ls += __shfl_xor(ls, 16);
  ls += __shfl_xor(ls, 32);
  float inv = 1.0f / ls;
  int row = (b * L + q0 + ra) * D + h * HD;
  short4v w0, w1;
#pragma unroll
  for (int r = 0; r < 4; ++r) { w0[r] = f2bf(o0[r] * inv); w1[r] = f2bf(o1[r] * inv); }
  *reinterpret_cast<short4v*>(ob + row + g * 4) = w0;
  *reinterpret_cast<short4v*>(ob + row + 16 + g * 4) = w1;
}

// ---------------- Kernel 3: out = O @ Wout (32x64 tiles, 4 blocks/CU) -------
__global__ __launch_bounds__(64) void out_gemm(const short* __restrict__ obuf,
                                               const short* __restrict__ wt,
                                               float* __restrict__ out) {
  int bid = blockIdx.x;
  int nt = bid & 3, mt = bid >> 2;      // 256 m-tiles x 4 n-tiles
  int m0 = mt * 32, n0 = nt * 64;
  int l = threadIdx.x, ra = l & 15, g = l >> 4;

  f32x4 acc[2][4] = {};
  for (int k0 = 0; k0 < 256; k0 += 32) {
    int kk = k0 + g * 8;
    short8 bfr[4], afr[2];
#pragma unroll
    for (int nf = 0; nf < 4; ++nf)
      bfr[nf] = *reinterpret_cast<const short8*>(&wt[(n0 + nf * 16 + ra) * 256 + kk]);
#pragma unroll
    for (int mf = 0; mf < 2; ++mf)
      afr[mf] = *reinterpret_cast<const short8*>(&obuf[(m0 + mf * 16 + ra) * 256 + kk]);
#pragma unroll
    for (int mf = 0; mf < 2; ++mf)
#pragma unroll
      for (int nf = 0; nf < 4; ++nf)
        acc[mf][nf] = __builtin_amdgcn_mfma_f32_16x16x32_bf16(afr[mf], bfr[nf], acc[mf][nf], 0, 0, 0);
  }
#pragma unroll
  for (int mf = 0; mf < 2; ++mf)
#pragma unroll
    for (int nf = 0; nf < 4; ++nf)
#pragma unroll
      for (int r = 0; r < 4; ++r)
        out[(m0 + mf * 16 + g * 4 + r) * 256 + n0 + nf * 16 + ra] = acc[mf][nf][r];
}

extern "C" void kernel_launch(void* const* d_in, const int* in_sizes, int n_in,
                              void* d_out, int out_size, void* d_ws, size_t ws_size,
                              hipStream_t stream) {
  const float* x    = (const float*)d_in[0];
  const float* bias = (const float*)d_in[1];
  const float* wqkv = (const float*)d_in[2];
  const float* wout = (const float*)d_in[3];
  float* out = (float*)d_out;

  short* xb     = (short*)d_ws;            // [8192,256]   2M shorts
  short* qb     = xb + B * L * D;          // [bh][L][HD]  2M
  short* kb     = qb + B * L * D;          // 2M
  short* vt     = kb + B * L * D;          // [bh][HD][L]  2M
  short* ob     = vt + B * L * D;          // [8192,256]   2M
  short* wqkvT  = ob + B * L * D;          // [768,256]
  short* woutT  = wqkvT + 768 * 256;       // [256,256]
  short* biasp  = woutT + 256 * 256;       // [L][L] bf16 frag-ordered *LOG2E, 4M

  prep_all<<<dim3(3328), dim3(256), 0, stream>>>(x, bias, wqkv, wout,
                                                 xb, biasp, wqkvT, woutT);
  qkv_gemm<<<dim3(1536), dim3(64), 0, stream>>>(xb, wqkvT, qb, kb, vt);
  attn_fwd<<<dim3(512), dim3(512), 0, stream>>>(qb, kb, vt, biasp, ob);
  out_gemm<<<dim3(1024), dim3(64), 0, stream>>>(ob, woutT, out);
}

// Round 19
// 82.811 us; speedup vs baseline: 1.0717x; 1.0717x over previous
//
#include <hip/hip_runtime.h>
#include <hip/hip_bf16.h>
#include <math.h>

#define B 4
#define L 2048
#define D 256
#define H 8
#define HD 32
#define KVB 64
#define SCALE 0.17677669529663687f
#define LOG2E 1.4426950408889634f
#define QSCL (SCALE * LOG2E)

typedef __attribute__((ext_vector_type(8))) short short8;
typedef __attribute__((ext_vector_type(4))) short short4v;
typedef __attribute__((ext_vector_type(4))) float f32x4;

__device__ inline short f2bf(float x) {
  union { float f; unsigned u; } c; c.f = x;
  unsigned r = (c.u + 0x7FFFu + ((c.u >> 16) & 1u)) >> 16;
  return (short)r;
}
__device__ inline float bf2f(short s) {
  union { unsigned u; float f; } c;
  c.u = ((unsigned)(unsigned short)s) << 16;
  return c.f;
}

// async 16B global->LDS DMA: LDS dest is wave-uniform base + lane*16 (m104);
// global source is per-lane. Compiler cannot demote this prefetch (no regs).
#define GLOAD_LDS16(gp, lp)                                                  \
  __builtin_amdgcn_global_load_lds(                                          \
      (const __attribute__((address_space(1))) unsigned*)(const void*)(gp),  \
      (__attribute__((address_space(3))) unsigned*)(void*)(lp), 16, 0, 0)

// Session journal (counter-evidenced):
// R5/R6: permlane*_swap with duplicated inputs is NOT a reduce primitive ->
//   __shfl_xor for reductions.
// R10: register K/V prefetch gets demoted (VGPR 60) -> LDS staging via
//   global_load_lds (R11: 124->51us attn).
// R12/R13: tight launch_bounds caps -> under-allocation + scratch spill
//   (WRITE_SIZE 531/12 MB). (512,4) = clean 48 VGPR.
// R14: in-block KV-split clean but slower (64 vs 51us) -> reverted.
// R16: v_pk_add_f32 + v_dot2_f32_bf16 (unvalidated) -> absmax 2.19. Rule:
//   one unproven primitive per round, validated in isolation, or not at all.
// R17: qkv 32x64 tiles = +4us regression (2x B-traffic) -> 64x64.
// R18: 4-buffer LDS rotation = +6us regression (burst staging + skew) ->
//   2-buffer barrier loop is the local optimum for this structure.
// R19: consolidation of best-measured pieces; no new levers.

// ---------------- prep_all: one launch for xb / bias / wqkvT / woutT --------
// grid sections: [0,1024) xb | [1024,3072) bias | [3072,3264) wqkvT |
// [3264,3328) woutT. 256 threads each.
__global__ __launch_bounds__(256) void prep_all(const float* __restrict__ x,
                                                const float* __restrict__ bias,
                                                const float* __restrict__ wqkv,
                                                const float* __restrict__ wout,
                                                short* __restrict__ xb,
                                                short* __restrict__ bp,
                                                short* __restrict__ wqkvT,
                                                short* __restrict__ woutT) {
  __shared__ short tile[32][33];
  int bid = blockIdx.x;
  if (bid < 1024) {
    // x f32 -> bf16
    int i = (bid * 256 + threadIdx.x) * 8;
    f32x4 a = *reinterpret_cast<const f32x4*>(x + i);
    f32x4 b = *reinterpret_cast<const f32x4*>(x + i + 4);
    short8 o;
#pragma unroll
    for (int j = 0; j < 4; ++j) { o[j] = f2bf(a[j]); o[4 + j] = f2bf(b[j]); }
    *reinterpret_cast<short8*>(xb + i) = o;
  } else if (bid < 3072) {
    // bias f32 [L][L] -> bf16 fragment-ordered, PRE-SCALED by LOG2E:
    // bp[q][kvt][g][i], i=4c+r  <->  bias[q][kvt*64 + 16c + g*4 + r] * LOG2E
    int base = ((bid - 1024) * 256 + threadIdx.x) * 8;
    int q = base >> 11;
    int rem = base & 2047;
    int kvt = rem >> 6;
    int wi = rem & 63;
    int g = wi >> 4;
    int c0 = (wi & 15) >> 2;       // 0 or 2
    const float* src = bias + (long)q * L + kvt * 64 + c0 * 16 + g * 4;
    f32x4 b0 = *reinterpret_cast<const f32x4*>(src);
    f32x4 b1 = *reinterpret_cast<const f32x4*>(src + 16);
    short8 o;
#pragma unroll
    for (int j = 0; j < 4; ++j) {
      o[j] = f2bf(b0[j] * LOG2E);
      o[4 + j] = f2bf(b1[j] * LOG2E);
    }
    *reinterpret_cast<short8*>(bp + base) = o;
  } else {
    // W [256,N] f32 -> W^T [N,256] bf16, LDS-tiled 32x32
    const float* w;
    short* wt;
    int idx, N;
    if (bid < 3264) { idx = bid - 3072; w = wqkv; wt = wqkvT; N = 768; }
    else            { idx = bid - 3264; w = wout; wt = woutT; N = 256; }
    int k0 = (idx & 7) * 32;
    int n0 = (idx >> 3) * 32;
    int tx = threadIdx.x & 31, ty = threadIdx.x >> 5;
#pragma unroll
    for (int i = 0; i < 32; i += 8)
      tile[ty + i][tx] = f2bf(w[(k0 + ty + i) * N + n0 + tx]);
    __syncthreads();
#pragma unroll
    for (int i = 0; i < 32; i += 8)
      wt[(n0 + ty + i) * 256 + k0 + tx] = tile[tx][ty + i];
  }
}

// ---------------- Kernel 1: qkv = xb @ Wqkv (64x64 tiles, R15-proven) -------
__global__ __launch_bounds__(64) void qkv_gemm(const short* __restrict__ xb,
                                               const short* __restrict__ wt,
                                               short* __restrict__ qb,
                                               short* __restrict__ kb,
                                               short* __restrict__ vt) {
  int bid = blockIdx.x;
  int mt = bid / 12, nt = bid % 12;
  int m0 = mt * 64, n0 = nt * 64;
  int l = threadIdx.x, ra = l & 15, g = l >> 4;

  f32x4 acc[4][4] = {};
  for (int k0 = 0; k0 < 256; k0 += 32) {
    int kk = k0 + g * 8;
    short8 bfr[4], afr[4];
#pragma unroll
    for (int nf = 0; nf < 4; ++nf)
      bfr[nf] = *reinterpret_cast<const short8*>(&wt[(n0 + nf * 16 + ra) * 256 + kk]);
#pragma unroll
    for (int mf = 0; mf < 4; ++mf)
      afr[mf] = *reinterpret_cast<const short8*>(&xb[(m0 + mf * 16 + ra) * 256 + kk]);
#pragma unroll
    for (int mf = 0; mf < 4; ++mf)
#pragma unroll
      for (int nf = 0; nf < 4; ++nf)
        acc[mf][nf] = __builtin_amdgcn_mfma_f32_16x16x32_bf16(afr[mf], bfr[nf], acc[mf][nf], 0, 0, 0);
  }

  int sec = n0 >> 8;   // 0=q 1=k 2=v (uniform per block)
  float scl = (sec == 0) ? QSCL : 1.0f;
#pragma unroll
  for (int nf = 0; nf < 4; ++nf) {
    int n = n0 + nf * 16 + ra;
    int c = n & 255;
    int h = c >> 5, d = c & 31;
#pragma unroll
    for (int mf = 0; mf < 4; ++mf) {
#pragma unroll
      for (int r = 0; r < 4; ++r) {
        int mm = m0 + mf * 16 + g * 4 + r;
        int b = mm >> 11, lpos = mm & 2047;
        short val = f2bf(acc[mf][nf][r] * scl);
        if (sec == 2) vt[((b * H + h) * HD + d) * L + lpos] = val;
        else {
          short* dst = (sec == 0) ? qb : kb;
          dst[((b * H + h) * L + lpos) * HD + d] = val;
        }
      }
    }
  }
}

// ---------------- Kernel 2: flash attention (R17-proven, LDS 2-phase) -------
// Block = 8 waves (512 thr) = 1 head x 8 q-tiles (128 q-rows). Per 64-kv tile
// K (4KB) + V^T (4KB) staged in LDS fragment-ordered lane-contiguous
// [subtile][lane][16B]; wave w stages subtile w via 1 global_load_lds(16B).
// Double-buffered; one __syncthreads per tile. Grid 512 = 2 blocks/CU.
// XCD = bid&7 -> heads 4x..4x+3: K/V 1MB/XCD L2-resident (FETCH 39MB).
__global__ __launch_bounds__(512, 4) void attn_fwd(const short* __restrict__ qb,
                                                   const short* __restrict__ kb,
                                                   const short* __restrict__ vt,
                                                   const short* __restrict__ bp,
                                                   short* __restrict__ ob) {
  __shared__ short kvlds[2][8][512];   // [buf][subtile][lane*8] = 16 KB

  int wid = threadIdx.x >> 6;
  int l = threadIdx.x & 63;
  int ra = l & 15, g = l >> 4;
  bool oddg = (g & 1);
  int x = blockIdx.x & 7;              // XCD id under round-robin dispatch
  int y = (blockIdx.x >> 3) & 3;
  int qblk = blockIdx.x >> 5;          // 0..15
  int bh = x * 4 + y;
  int q0 = qblk * 128 + wid * 16;

  const short* kbase = kb + bh * (L * HD);
  const short* vbase = vt + bh * (HD * L);
  const short* bpbase = bp + (q0 + ra) * L + g * 16;

  short8 bq = *reinterpret_cast<const short8*>(qb + (bh * L + q0 + ra) * HD + g * 8);

  // Per-wave staging source (lane-resolved). Wave w<4 stages K subtile w
  // (rows 16w+ra, cols g*8..); wave w>=4 stages V subtile j=w-4
  // (rows (j>>1)*16+ra of V^T, cols kv+(j&1)*32+g*8).
  const short* gsrc0;
  int gstep;
  if (wid < 4) { gsrc0 = kbase + (16 * wid + ra) * HD + g * 8; gstep = KVB * HD; }
  else {
    int j = wid - 4;
    gsrc0 = vbase + ((j >> 1) * 16 + ra) * L + (j & 1) * 32 + g * 8;
    gstep = KVB;
  }

  f32x4 o0 = {}, o1 = {}, zf = {};
  float mrun = -1e30f, lsum = 0.f;
  short8 bbX[2], bbY[2];

  auto STAGE = [&](int buf, int t) {
    GLOAD_LDS16(gsrc0 + (size_t)t * gstep, &kvlds[buf][wid][0]);
  };
  auto BLOAD = [&](short8 (&bb)[2], int t) {
    const short* p = bpbase + t * KVB;
    bb[0] = *reinterpret_cast<const short8*>(p);
    bb[1] = *reinterpret_cast<const short8*>(p + 8);
  };

  auto TILE = [&](int buf, short8 (&bb)[2]) {
    const short* base = &kvlds[buf][0][0];
    short8 ak0 = *reinterpret_cast<const short8*>(base + 0 * 512 + l * 8);
    short8 ak1 = *reinterpret_cast<const short8*>(base + 1 * 512 + l * 8);
    short8 ak2 = *reinterpret_cast<const short8*>(base + 2 * 512 + l * 8);
    short8 ak3 = *reinterpret_cast<const short8*>(base + 3 * 512 + l * 8);
    short8 va0 = *reinterpret_cast<const short8*>(base + 4 * 512 + l * 8);
    short8 va1 = *reinterpret_cast<const short8*>(base + 5 * 512 + l * 8);
    short8 va2 = *reinterpret_cast<const short8*>(base + 6 * 512 + l * 8);
    short8 va3 = *reinterpret_cast<const short8*>(base + 7 * 512 + l * 8);

    f32x4 s0 = __builtin_amdgcn_mfma_f32_16x16x32_bf16(ak0, bq, zf, 0, 0, 0);
    f32x4 s1 = __builtin_amdgcn_mfma_f32_16x16x32_bf16(ak1, bq, zf, 0, 0, 0);
    f32x4 s2 = __builtin_amdgcn_mfma_f32_16x16x32_bf16(ak2, bq, zf, 0, 0, 0);
    f32x4 s3 = __builtin_amdgcn_mfma_f32_16x16x32_bf16(ak3, bq, zf, 0, 0, 0);

    // v = s + bias (bias pre-scaled by LOG2E in prep -> plain add, not fma)
    float v[16];
#pragma unroll
    for (int r = 0; r < 4; ++r) {
      v[r]      = s0[r] + bf2f(bb[0][r]);
      v[4 + r]  = s1[r] + bf2f(bb[0][4 + r]);
      v[8 + r]  = s2[r] + bf2f(bb[1][r]);
      v[12 + r] = s3[r] + bf2f(bb[1][4 + r]);
    }
    float t0 = fmaxf(fmaxf(v[0], v[1]), v[2]);
    float t1 = fmaxf(fmaxf(v[3], v[4]), v[5]);
    float t2 = fmaxf(fmaxf(v[6], v[7]), v[8]);
    float t3 = fmaxf(fmaxf(v[9], v[10]), v[11]);
    float t4m = fmaxf(fmaxf(v[12], v[13]), v[14]);
    float pml = fmaxf(fmaxf(fmaxf(t0, t1), t2), fmaxf(fmaxf(t3, t4m), v[15]));

    // mrun wave-uniform -> per-lane __all check; shfls only on rare rescale.
    if (!__all(pml <= mrun + 8.0f)) {
      float pm = fmaxf(pml, __shfl_xor(pml, 16));
      pm = fmaxf(pm, __shfl_xor(pm, 32));
      float mnew = fmaxf(mrun, pm);
      float ad = mrun - mnew, al;
      asm("v_exp_f32 %0, %1" : "=v"(al) : "v"(ad));
      lsum *= al;
#pragma unroll
      for (int r = 0; r < 4; ++r) { o0[r] *= al; o1[r] *= al; }
      mrun = mnew;
    }
    float m = mrun;
#pragma unroll
    for (int i = 0; i < 16; ++i) {
      float xv = v[i] - m;
      asm("v_exp_f32 %0, %1" : "=v"(v[i]) : "v"(xv));
    }
    // tree-reduce the per-lane partial (depth 4, not a 16-long serial chain)
    float p01 = (v[0] + v[1]) + (v[2] + v[3]);
    float p23 = (v[4] + v[5]) + (v[6] + v[7]);
    float p45 = (v[8] + v[9]) + (v[10] + v[11]);
    float p67 = (v[12] + v[13]) + (v[14] + v[15]);
    lsum += (p01 + p23) + (p45 + p67);

#pragma unroll
    for (int ch = 0; ch < 2; ++ch) {
      const float* pc = v + ch * 8;
      unsigned w01, w23, w45, w67;
      asm("v_cvt_pk_bf16_f32 %0, %1, %2" : "=v"(w01) : "v"(pc[0]), "v"(pc[1]));
      asm("v_cvt_pk_bf16_f32 %0, %1, %2" : "=v"(w23) : "v"(pc[2]), "v"(pc[3]));
      asm("v_cvt_pk_bf16_f32 %0, %1, %2" : "=v"(w45) : "v"(pc[4]), "v"(pc[5]));
      asm("v_cvt_pk_bf16_f32 %0, %1, %2" : "=v"(w67) : "v"(pc[6]), "v"(pc[7]));
      asm("v_permlane32_swap_b32 %0, %1" : "+v"(w01), "+v"(w45));  // distinct ops: proven
      asm("v_permlane32_swap_b32 %0, %1" : "+v"(w23), "+v"(w67));
      unsigned z1 = oddg ? w01 : w45;
      unsigned z2 = oddg ? w23 : w67;
      unsigned y1 = (unsigned)__shfl_xor((int)z1, 16);   // exact permute
      unsigned y2 = (unsigned)__shfl_xor((int)z2, 16);
      union { unsigned u[4]; short8 s; } pb;
      pb.u[0] = oddg ? y1 : w01;
      pb.u[1] = oddg ? y2 : w23;
      pb.u[2] = oddg ? w45 : y1;
      pb.u[3] = oddg ? w67 : y2;
      o0 = __builtin_amdgcn_mfma_f32_16x16x32_bf16(ch ? va1 : va0, pb.s, o0, 0, 0, 0);
      o1 = __builtin_amdgcn_mfma_f32_16x16x32_bf16(ch ? va3 : va2, pb.s, o1, 0, 0, 0);
    }
  };

  // ---- 2-phase pipeline: stage t+1 while computing t; barrier drains DMA ---
  STAGE(0, 0);
  BLOAD(bbX, 0);
  __syncthreads();
  for (int t = 0; t < 32; t += 2) {
    STAGE(1, t + 1);
    BLOAD(bbY, t + 1);
    TILE(0, bbX);
    __syncthreads();
    if (t + 2 < 32) { STAGE(0, t + 2); BLOAD(bbX, t + 2); }
    TILE(1, bbY);
    __syncthreads();
  }

  int b = bh >> 3, h = bh & 7;
  float ls = lsum;
  ls += __shfl_xor(ls, 16);
  ls += __shfl_xor(ls, 32);
  float inv = 1.0f / ls;
  int row = (b * L + q0 + ra) * D + h * HD;
  short4v w0, w1;
#pragma unroll
  for (int r = 0; r < 4; ++r) { w0[r] = f2bf(o0[r] * inv); w1[r] = f2bf(o1[r] * inv); }
  *reinterpret_cast<short4v*>(ob + row + g * 4) = w0;
  *reinterpret_cast<short4v*>(ob + row + 16 + g * 4) = w1;
}

// ---------------- Kernel 3: out = O @ Wout (32x64 tiles, 4 blocks/CU) -------
__global__ __launch_bounds__(64) void out_gemm(const short* __restrict__ obuf,
                                               const short* __restrict__ wt,
                                               float* __restrict__ out) {
  int bid = blockIdx.x;
  int nt = bid & 3, mt = bid >> 2;      // 256 m-tiles x 4 n-tiles
  int m0 = mt * 32, n0 = nt * 64;
  int l = threadIdx.x, ra = l & 15, g = l >> 4;

  f32x4 acc[2][4] = {};
  for (int k0 = 0; k0 < 256; k0 += 32) {
    int kk = k0 + g * 8;
    short8 bfr[4], afr[2];
#pragma unroll
    for (int nf = 0; nf < 4; ++nf)
      bfr[nf] = *reinterpret_cast<const short8*>(&wt[(n0 + nf * 16 + ra) * 256 + kk]);
#pragma unroll
    for (int mf = 0; mf < 2; ++mf)
      afr[mf] = *reinterpret_cast<const short8*>(&obuf[(m0 + mf * 16 + ra) * 256 + kk]);
#pragma unroll
    for (int mf = 0; mf < 2; ++mf)
#pragma unroll
      for (int nf = 0; nf < 4; ++nf)
        acc[mf][nf] = __builtin_amdgcn_mfma_f32_16x16x32_bf16(afr[mf], bfr[nf], acc[mf][nf], 0, 0, 0);
  }
#pragma unroll
  for (int mf = 0; mf < 2; ++mf)
#pragma unroll
    for (int nf = 0; nf < 4; ++nf)
#pragma unroll
      for (int r = 0; r < 4; ++r)
        out[(m0 + mf * 16 + g * 4 + r) * 256 + n0 + nf * 16 + ra] = acc[mf][nf][r];
}

extern "C" void kernel_launch(void* const* d_in, const int* in_sizes, int n_in,
                              void* d_out, int out_size, void* d_ws, size_t ws_size,
                              hipStream_t stream) {
  const float* x    = (const float*)d_in[0];
  const float* bias = (const float*)d_in[1];
  const float* wqkv = (const float*)d_in[2];
  const float* wout = (const float*)d_in[3];
  float* out = (float*)d_out;

  short* xb     = (short*)d_ws;            // [8192,256]   2M shorts
  short* qb     = xb + B * L * D;          // [bh][L][HD]  2M
  short* kb     = qb + B * L * D;          // 2M
  short* vt     = kb + B * L * D;          // [bh][HD][L]  2M
  short* ob     = vt + B * L * D;          // [8192,256]   2M
  short* wqkvT  = ob + B * L * D;          // [768,256]
  short* woutT  = wqkvT + 768 * 256;       // [256,256]
  short* biasp  = woutT + 256 * 256;       // [L][L] bf16 frag-ordered *LOG2E, 4M

  prep_all<<<dim3(3328), dim3(256), 0, stream>>>(x, bias, wqkv, wout,
                                                 xb, biasp, wqkvT, woutT);
  qkv_gemm<<<dim3(1536), dim3(64), 0, stream>>>(xb, wqkvT, qb, kb, vt);
  attn_fwd<<<dim3(512), dim3(512), 0, stream>>>(qb, kb, vt, biasp, ob);
  out_gemm<<<dim3(1024), dim3(64), 0, stream>>>(ob, woutT, out);
}